// Round 13
// baseline (272.499 us; speedup 1.0000x reference)
//
#include <hip/hip_runtime.h>

#define B_   2048
#define T1_  31
#define D_   128
#define MB_  8

typedef __attribute__((ext_vector_type(8))) short bf16x8;
typedef __attribute__((ext_vector_type(4))) float f32x4;
typedef __attribute__((ext_vector_type(2))) float f32x2;

__device__ __forceinline__ unsigned cvt_pk_bf16(float lo, float hi) {
    unsigned r;
    asm("v_cvt_pk_bf16_f32 %0, %1, %2" : "=v"(r) : "v"(lo), "v"(hi));
    return r;
}
__device__ __forceinline__ float rcpf_(float x) { return __builtin_amdgcn_rcpf(x); }
__device__ __forceinline__ float sigf(float x)  { return rcpf_(1.0f + __expf(-x)); }
__device__ __forceinline__ float tanhf_(float x) {
    float ax = fabsf(x);
    float t  = 1.0f - 2.0f * rcpf_(__expf(2.0f * ax) + 1.0f);
    return copysignf(t, x);
}

#define BAR_LDS() asm volatile("s_waitcnt lgkmcnt(0)\n\ts_barrier" ::: "memory")

// Instrumented kernel: PRE_REP repetitions of the pre-phase, LOOP_REP passes of
// the recurrent loop (state reset between). <1,1> == the round-12 kernel.
// Probes <1,4> and <4,1> are launched BEFORE the real <1,1>, which overwrites
// d_out with correct values. Per-dispatch rocprof durs decompose phase costs.
template<int PRE_REP, int LOOP_REP>
__global__ __launch_bounds__(512, 2) void enc_k(
    const float* __restrict__ in,    // [B][31][128]
    const float* __restrict__ Wih,   // [512][128]
    const float* __restrict__ Whh,   // [512][128]
    const float* __restrict__ bih,   // [512]
    const float* __restrict__ bhh,   // [512]
    const float* __restrict__ aw,    // [287]
    float* __restrict__ outW,        // [B][31][128]
    float* __restrict__ outE)        // [B][31][128]
{
    const int tid  = threadIdx.x;
    const int lane = tid & 63;
    const int wv   = tid >> 6;        // wave 0..7
    const int b0   = blockIdx.x * MB_;
    const int l15  = lane & 15;
    const int lq   = lane >> 4;

    __shared__ __align__(16) char Xw[30 * MB_ * 256];   // 61440 B
    __shared__ __align__(16) char Hs[2 * MB_ * 256];    // 4096 B

    // ---------------- weight fragments -> registers ----------------------------
    bf16x8 bw[4][8];
    #pragma unroll
    for (int s = 0; s < 4; ++s) {
        int n = s * 128 + wv * 16 + l15;
        #pragma unroll
        for (int kf = 0; kf < 8; ++kf) {
            int kb = kf * 32 + lq * 8;
            const float* wp = (kf < 4) ? (Wih + n * D_ + kb) : (Whh + n * D_ + (kb - 128));
            float4 fa = *(const float4*)(wp);
            float4 fb = *(const float4*)(wp + 4);
            union { bf16x8 v; unsigned u[4]; } tmp;
            tmp.u[0] = cvt_pk_bf16(fa.x, fa.y);
            tmp.u[1] = cvt_pk_bf16(fa.z, fa.w);
            tmp.u[2] = cvt_pk_bf16(fb.x, fb.y);
            tmp.u[3] = cvt_pk_bf16(fb.z, fb.w);
            bw[s][kf] = tmp.v;
        }
    }
    const int col = wv * 16 + l15;
    const float bs0 = bih[col]           + bhh[col];
    const float bs1 = bih[128 + col]     + bhh[128 + col];
    const float bs2 = bih[256 + col]     + bhh[256 + col];
    const float bs3 = bih[384 + col]     + bhh[384 + col];

    const int mg = wv;
    const int dh = lane;
    const int d0 = 2 * dh;
    const float* pin = in + (size_t)(b0 + mg) * (T1_ * D_) + d0;
    const int wxbyte = (4 * dh) ^ (mg << 4);
    float* outWp = outW + (size_t)(b0 + mg) * (T1_ * D_) + d0;

    float2 xc[T1_];
    float a0 = 0.f, a1 = 0.f;
    unsigned wx30 = 0;

    // =============== PRE-PHASE (repeated PRE_REP times for probing) ============
    #pragma unroll 1
    for (int pr = 0; pr < PRE_REP; ++pr) {
        float xs0 = 0.f, xs1 = 0.f;
        #pragma unroll
        for (int t = 0; t < T1_; ++t) {
            float wt = aw[2 * D_ + t];
            xc[t] = *(const float2*)(pin + t * D_);
            xs0 = fmaf(wt, xc[t].x, xs0);
            xs1 = fmaf(wt, xc[t].y, xs1);
        }
        float* attnS = (float*)Xw;     // [8][128] overlay on slots 0-1
        attnS[mg * 128 + d0]     = xs0;
        attnS[mg * 128 + d0 + 1] = xs1;

        float v0 = attnS[mg * 128 + lane];
        float v1 = attnS[mg * 128 + lane + 64];
        float mx = fmaxf(v0, v1);
        #pragma unroll
        for (int o = 32; o > 0; o >>= 1) mx = fmaxf(mx, __shfl_xor(mx, o));
        float e0 = __expf(v0 - mx), e1 = __expf(v1 - mx);
        float ss = e0 + e1;
        #pragma unroll
        for (int o = 32; o > 0; o >>= 1) ss += __shfl_xor(ss, o);
        float inv = 1.0f / ss;
        attnS[mg * 128 + lane]      = e0 * inv;
        attnS[mg * 128 + lane + 64] = e1 * inv;
        a0 = attnS[mg * 128 + d0];
        a1 = attnS[mg * 128 + d0 + 1];
        BAR_LDS();                     // overlay clobber hazard only

        #pragma unroll
        for (int t = 0; t < T1_; ++t) {
            float w0 = a0 * xc[t].x, w1 = a1 * xc[t].y;
            f32x2 wsv; wsv[0] = w0; wsv[1] = w1;
            __builtin_nontemporal_store(wsv, (f32x2*)(outWp + t * D_));
            unsigned u = cvt_pk_bf16(w0, w1);
            if (t < 30) *(unsigned*)(Xw + t * 2048 + mg * 256 + wxbyte) = u;
            else        wx30 = u;
        }
        ((unsigned*)Hs)[tid]       = 0u;
        ((unsigned*)Hs)[tid + 512] = 0u;
        BAR_LDS();
    }

    // =============== RECURRENT LOOP (LOOP_REP passes for probing) ==============
    const int arow = l15 & 7;
    const int asw  = arow << 4;
    const int rb = ((lane & 31) >> 4) * 4 + ((lane >> 5) << 1);
    const bool hi32 = (lane >= 32);
    float* outE0 = outE + (size_t)(b0 + rb)     * (T1_ * D_) + col;
    float* outE1 = outE + (size_t)(b0 + rb + 1) * (T1_ * D_) + col;

    #pragma unroll 1
    for (int lp = 0; lp < LOOP_REP; ++lp) {
        float cs0 = 0.f, cs1 = 0.f;
        bf16x8 wxfr[4];
        #pragma unroll
        for (int kf = 0; kf < 4; ++kf)
            wxfr[kf] = *(const bf16x8*)(Xw + arow * 256 + ((kf * 64 + lq * 16) ^ asw));

        for (int t = 0; t < T1_; ++t) {
            const char* hp = Hs + (t & 1) * 2048 + arow * 256;
            bf16x8 hfr[4];
            #pragma unroll
            for (int kf = 0; kf < 4; ++kf)
                hfr[kf] = *(const bf16x8*)(hp + ((kf * 64 + lq * 16) ^ asw));

            if (t == 1)
                *(unsigned*)(Xw + mg * 256 + wxbyte) = wx30;

            f32x4 accx[4];
            #pragma unroll
            for (int s = 0; s < 4; ++s) {
                f32x4 a_ = {0.f, 0.f, 0.f, 0.f};
                #pragma unroll
                for (int kf = 0; kf < 4; ++kf)
                    a_ = __builtin_amdgcn_mfma_f32_16x16x32_bf16(wxfr[kf], bw[s][kf], a_, 0, 0, 0);
                accx[s] = a_;
            }

            f32x4 acc[4];
            #pragma unroll
            for (int s = 0; s < 4; ++s) {
                f32x4 zA = {0.f, 0.f, 0.f, 0.f};
                f32x4 zB = {0.f, 0.f, 0.f, 0.f};
                zA = __builtin_amdgcn_mfma_f32_16x16x32_bf16(hfr[0], bw[s][4], zA, 0, 0, 0);
                zB = __builtin_amdgcn_mfma_f32_16x16x32_bf16(hfr[2], bw[s][6], zB, 0, 0, 0);
                zA = __builtin_amdgcn_mfma_f32_16x16x32_bf16(hfr[1], bw[s][5], zA, 0, 0, 0);
                zB = __builtin_amdgcn_mfma_f32_16x16x32_bf16(hfr[3], bw[s][7], zB, 0, 0, 0);
                acc[s] = accx[s] + zA + zB;
            }

            if (t < 30) {
                int slot = (t + 1 == 30) ? 0 : (t + 1);
                #pragma unroll
                for (int kf = 0; kf < 4; ++kf)
                    wxfr[kf] = *(const bf16x8*)(Xw + slot * 2048 + arow * 256 + ((kf * 64 + lq * 16) ^ asw));
            }

            float gq0[4], gq1[4];
            #pragma unroll
            for (int s = 0; s < 4; ++s) {
                gq0[s] = hi32 ? acc[s][2] : acc[s][0];
                gq1[s] = hi32 ? acc[s][3] : acc[s][1];
            }

            float iv, fv, gv, ov, cn, hh0, hh1;
            iv = gq0[0] + bs0; fv = gq0[1] + bs1; gv = gq0[2] + bs2; ov = gq0[3] + bs3;
            cn = sigf(fv) * cs0 + sigf(iv) * tanhf_(gv); cs0 = cn;
            hh0 = sigf(ov) * tanhf_(cn);

            iv = gq1[0] + bs0; fv = gq1[1] + bs1; gv = gq1[2] + bs2; ov = gq1[3] + bs3;
            cn = sigf(fv) * cs1 + sigf(iv) * tanhf_(gv); cs1 = cn;
            hh1 = sigf(ov) * tanhf_(cn);

            unsigned hu = cvt_pk_bf16(hh0, hh1);

            if (t < 30) {
                char* hw = Hs + ((t + 1) & 1) * 2048;
                *(unsigned short*)(hw + rb * 256       + ((2 * col) ^ (rb << 4)))       = (unsigned short)(hu & 0xffffu);
                *(unsigned short*)(hw + (rb + 1) * 256 + ((2 * col) ^ ((rb + 1) << 4))) = (unsigned short)(hu >> 16);
            }
            __builtin_nontemporal_store(hh0, outE0 + t * D_);
            __builtin_nontemporal_store(hh1, outE1 + t * D_);

            BAR_LDS();
        }

        if (lp + 1 < LOOP_REP) {       // reset recurrent state for next probe pass
            ((unsigned*)Hs)[tid]       = 0u;
            ((unsigned*)Hs)[tid + 512] = 0u;
            BAR_LDS();
        }
    }
}

extern "C" void kernel_launch(void* const* d_in, const int* in_sizes, int n_in,
                              void* d_out, int out_size, void* d_ws, size_t ws_size,
                              hipStream_t stream) {
    const float* in  = (const float*)d_in[0];
    const float* Wih = (const float*)d_in[1];
    const float* Whh = (const float*)d_in[2];
    const float* bih = (const float*)d_in[3];
    const float* bhh = (const float*)d_in[4];
    const float* aw  = (const float*)d_in[5];

    float* outW = (float*)d_out;
    float* outE = outW + (size_t)B_ * T1_ * D_;

    // Probes first (their garbage is overwritten), real kernel LAST.
    enc_k<1, 4><<<dim3(B_ / MB_), dim3(512), 0, stream>>>(in, Wih, Whh, bih, bhh, aw, outW, outE);
    enc_k<4, 1><<<dim3(B_ / MB_), dim3(512), 0, stream>>>(in, Wih, Whh, bih, bhh, aw, outW, outE);
    enc_k<1, 1><<<dim3(B_ / MB_), dim3(512), 0, stream>>>(in, Wih, Whh, bih, bhh, aw, outW, outE);
}

// Round 14
// 70.113 us; speedup vs baseline: 3.8866x; 3.8866x over previous
//
#include <hip/hip_runtime.h>

#define B_   2048
#define T1_  31
#define D_   128
#define MB_  8
#define WS_PER_BLK 65536ull

typedef __attribute__((ext_vector_type(8))) short bf16x8;
typedef __attribute__((ext_vector_type(4))) float f32x4;
typedef __attribute__((ext_vector_type(2))) float f32x2;

__device__ __forceinline__ unsigned cvt_pk_bf16(float lo, float hi) {
    unsigned r;
    asm("v_cvt_pk_bf16_f32 %0, %1, %2" : "=v"(r) : "v"(lo), "v"(hi));
    return r;
}
__device__ __forceinline__ float rcpf_(float x) { return __builtin_amdgcn_rcpf(x); }
__device__ __forceinline__ float sigf(float x)  { return rcpf_(1.0f + __expf(-x)); }
__device__ __forceinline__ float tanhf_(float x) {
    float ax = fabsf(x);
    float t  = 1.0f - 2.0f * rcpf_(__expf(2.0f * ax) + 1.0f);
    return copysignf(t, x);
}

#define BAR_LDS() asm volatile("s_waitcnt lgkmcnt(0)\n\ts_barrier" ::: "memory")

// ============================ primary kernel =================================
// wx staging lives in GLOBAL scratch (L2-hot), written in fragment-ready layout
// by the pre-phase. The recurrent loop reads wx via global loads prefetched one
// full step ahead (no barrier coupling); LDS holds only the 4 KB h double-buffer.
__global__ __launch_bounds__(512, 2) void enc_ws(
    const float* __restrict__ in,    // [B][31][128]
    const float* __restrict__ Wih,   // [512][128]
    const float* __restrict__ Whh,   // [512][128]
    const float* __restrict__ bih,   // [512]
    const float* __restrict__ bhh,   // [512]
    const float* __restrict__ aw,    // [287]
    float* __restrict__ outW,        // [B][31][128]
    float* __restrict__ outE,        // [B][31][128]
    char* __restrict__ ws)           // >= 64 KB per block
{
    const int tid  = threadIdx.x;
    const int lane = tid & 63;
    const int wv   = tid >> 6;        // wave 0..7
    const int b0   = blockIdx.x * MB_;
    const int l15  = lane & 15;
    const int lq   = lane >> 4;

    __shared__ __align__(16) char Hs[2 * 2048];   // h dbuf: [2][8 rows][256 B]

    // ---------------- weight fragments -> registers (AGPR side) ----------------
    bf16x8 bw[4][8];
    #pragma unroll
    for (int s = 0; s < 4; ++s) {
        int n = s * 128 + wv * 16 + l15;
        #pragma unroll
        for (int kf = 0; kf < 8; ++kf) {
            int kb = kf * 32 + lq * 8;
            const float* wp = (kf < 4) ? (Wih + n * D_ + kb) : (Whh + n * D_ + (kb - 128));
            float4 fa = *(const float4*)(wp);
            float4 fb = *(const float4*)(wp + 4);
            union { bf16x8 v; unsigned u[4]; } tmp;
            tmp.u[0] = cvt_pk_bf16(fa.x, fa.y);
            tmp.u[1] = cvt_pk_bf16(fa.z, fa.w);
            tmp.u[2] = cvt_pk_bf16(fb.x, fb.y);
            tmp.u[3] = cvt_pk_bf16(fb.z, fb.w);
            bw[s][kf] = tmp.v;
        }
    }
    const int col = wv * 16 + l15;
    const float bsv[4] = { bih[col]         + bhh[col],
                           bih[128 + col]   + bhh[128 + col],
                           bih[256 + col]   + bhh[256 + col],
                           bih[384 + col]   + bhh[384 + col] };

    // ---------------- pre-phase pass 1: x_score + pure-shfl softmax ------------
    const int mg = wv;
    const int d0 = 2 * lane;
    const float* pin = in + (size_t)(b0 + mg) * (T1_ * D_) + d0;

    float xs0 = 0.f, xs1 = 0.f;
    #pragma unroll
    for (int t = 0; t < T1_; ++t) {
        float wt = aw[2 * D_ + t];
        float2 a = *(const float2*)(pin + t * D_);
        xs0 = fmaf(wt, a.x, xs0);
        xs1 = fmaf(wt, a.y, xs1);
    }
    float mx = fmaxf(xs0, xs1);
    #pragma unroll
    for (int o = 32; o > 0; o >>= 1) mx = fmaxf(mx, __shfl_xor(mx, o));
    float e0 = __expf(xs0 - mx), e1 = __expf(xs1 - mx);
    float ss = e0 + e1;
    #pragma unroll
    for (int o = 32; o > 0; o >>= 1) ss += __shfl_xor(ss, o);
    float inv = 1.0f / ss;
    const float a0 = e0 * inv;
    const float a1 = e1 * inv;

    // ---------------- pre-phase pass 2: outW (NT) + wx -> global ws ------------
    char* wsb = ws + ((size_t)blockIdx.x * WS_PER_BLK);
    float* outWp = outW + (size_t)(b0 + mg) * (T1_ * D_) + d0;
    #pragma unroll
    for (int t = 0; t < T1_; ++t) {
        float2 xv = *(const float2*)(pin + t * D_);          // L2-hot re-read
        float w0 = a0 * xv.x, w1 = a1 * xv.y;
        f32x2 wsv; wsv[0] = w0; wsv[1] = w1;
        __builtin_nontemporal_store(wsv, (f32x2*)(outWp + t * D_));
        // plain store (want L2 residency): [t][row=mg][k] bf16, 2048 B per t
        *(unsigned*)(wsb + t * 2048 + mg * 256 + 4 * lane) = cvt_pk_bf16(w0, w1);
    }
    ((unsigned*)Hs)[tid]       = 0u;   // h(0) = 0, both buffers (4 KB total)
    ((unsigned*)Hs)[tid + 512] = 0u;
    __syncthreads();                   // full drain: ws writes visible block-wide

    // ---------------- recurrent loop ------------------------------------------
    const int arow = l15 & 7;          // A-frag row (rows 8-15 replicate 0-7)
    const int asw  = arow << 4;
    const int rb   = ((lane & 31) >> 4) * 4 + ((lane >> 5) << 1);
    const bool hi32 = (lane >= 32);
    float cs0 = 0.f, cs1 = 0.f;
    float* outE0 = outE + (size_t)(b0 + rb)     * (T1_ * D_) + col;
    float* outE1 = outE + (size_t)(b0 + rb + 1) * (T1_ * D_) + col;

    const char* wsf = wsb + arow * 256 + lq * 16;   // this lane's fragment base
    bf16x8 wxc[4], wxn[4];
    #pragma unroll
    for (int kf = 0; kf < 4; ++kf)
        wxc[kf] = *(const bf16x8*)(wsf + kf * 64);  // t = 0 fragments

    for (int t = 0; t < T1_; ++t) {
        // h fragments (only LDS traffic in the loop besides the 2 h writes)
        const char* hp = Hs + (t & 1) * 2048 + arow * 256;
        bf16x8 hfr[4];
        #pragma unroll
        for (int kf = 0; kf < 4; ++kf)
            hfr[kf] = *(const bf16x8*)(hp + ((kf * 64 + lq * 16) ^ asw));

        // prefetch next step's wx fragments from global (lands during this step)
        if (t < 30) {
            const char* wn = wsf + (t + 1) * 2048;
            #pragma unroll
            for (int kf = 0; kf < 4; ++kf)
                wxn[kf] = *(const bf16x8*)(wn + kf * 64);
        }

        // gates: wx-chain seeded with bias; h-chain zero-seeded; merged
        f32x4 acc[4];
        #pragma unroll
        for (int s = 0; s < 4; ++s) {
            float b = bsv[s];
            f32x4 aA = {b, b, b, b};
            f32x4 aB = {0.f, 0.f, 0.f, 0.f};
            #pragma unroll
            for (int kf = 0; kf < 4; ++kf)
                aA = __builtin_amdgcn_mfma_f32_16x16x32_bf16(wxc[kf], bw[s][kf],     aA, 0, 0, 0);
            #pragma unroll
            for (int kf = 0; kf < 4; ++kf)
                aB = __builtin_amdgcn_mfma_f32_16x16x32_bf16(hfr[kf], bw[s][4 + kf], aB, 0, 0, 0);
            acc[s] = aA + aB;
        }

        // row select via replication: lanes>=32 hold rows rb,rb+1 in acc[2],acc[3]
        float gq0[4], gq1[4];
        #pragma unroll
        for (int s = 0; s < 4; ++s) {
            gq0[s] = hi32 ? acc[s][2] : acc[s][0];
            gq1[s] = hi32 ? acc[s][3] : acc[s][1];
        }

        // elementwise, two independent cells interleaved
        float sf0 = sigf(gq0[1]), sf1 = sigf(gq1[1]);
        float si0 = sigf(gq0[0]), si1 = sigf(gq1[0]);
        float tg0 = tanhf_(gq0[2]), tg1 = tanhf_(gq1[2]);
        float so0 = sigf(gq0[3]), so1 = sigf(gq1[3]);
        float cn0 = sf0 * cs0 + si0 * tg0;  cs0 = cn0;
        float cn1 = sf1 * cs1 + si1 * tg1;  cs1 = cn1;
        float hh0 = so0 * tanhf_(cn0);
        float hh1 = so1 * tanhf_(cn1);
        unsigned hu = cvt_pk_bf16(hh0, hh1);

        // LDS h write (gates the barrier); global stores after (don't gate)
        if (t < 30) {
            char* hw = Hs + ((t + 1) & 1) * 2048;
            *(unsigned short*)(hw + rb * 256       + ((2 * col) ^ (rb << 4)))       = (unsigned short)(hu & 0xffffu);
            *(unsigned short*)(hw + (rb + 1) * 256 + ((2 * col) ^ ((rb + 1) << 4))) = (unsigned short)(hu >> 16);
        }
        __builtin_nontemporal_store(hh0, outE0 + t * D_);
        __builtin_nontemporal_store(hh1, outE1 + t * D_);

        #pragma unroll
        for (int kf = 0; kf < 4; ++kf) wxc[kf] = wxn[kf];   // counted vmcnt wait here

        BAR_LDS();   // LDS-only visibility; global ops stay in flight
    }
}

// ============================ fallback (round-12, proven) ====================
__global__ __launch_bounds__(512, 2) void enc_fused(
    const float* __restrict__ in, const float* __restrict__ Wih,
    const float* __restrict__ Whh, const float* __restrict__ bih,
    const float* __restrict__ bhh, const float* __restrict__ aw,
    float* __restrict__ outW, float* __restrict__ outE)
{
    const int tid  = threadIdx.x;
    const int lane = tid & 63;
    const int wv   = tid >> 6;
    const int b0   = blockIdx.x * MB_;
    const int l15  = lane & 15;
    const int lq   = lane >> 4;

    __shared__ __align__(16) char Xw[30 * MB_ * 256];
    __shared__ __align__(16) char Hs[2 * MB_ * 256];

    bf16x8 bw[4][8];
    #pragma unroll
    for (int s = 0; s < 4; ++s) {
        int n = s * 128 + wv * 16 + l15;
        #pragma unroll
        for (int kf = 0; kf < 8; ++kf) {
            int kb = kf * 32 + lq * 8;
            const float* wp = (kf < 4) ? (Wih + n * D_ + kb) : (Whh + n * D_ + (kb - 128));
            float4 fa = *(const float4*)(wp);
            float4 fb = *(const float4*)(wp + 4);
            union { bf16x8 v; unsigned u[4]; } tmp;
            tmp.u[0] = cvt_pk_bf16(fa.x, fa.y);
            tmp.u[1] = cvt_pk_bf16(fa.z, fa.w);
            tmp.u[2] = cvt_pk_bf16(fb.x, fb.y);
            tmp.u[3] = cvt_pk_bf16(fb.z, fb.w);
            bw[s][kf] = tmp.v;
        }
    }
    const int col = wv * 16 + l15;
    const float bs0 = bih[col]         + bhh[col];
    const float bs1 = bih[128 + col]   + bhh[128 + col];
    const float bs2 = bih[256 + col]   + bhh[256 + col];
    const float bs3 = bih[384 + col]   + bhh[384 + col];

    const int mg = wv;
    const int dh = lane;
    const int d0 = 2 * dh;
    const float* pin = in + (size_t)(b0 + mg) * (T1_ * D_) + d0;

    float2 xc[T1_];
    float xs0 = 0.f, xs1 = 0.f;
    #pragma unroll
    for (int t = 0; t < T1_; ++t) {
        float wt = aw[2 * D_ + t];
        xc[t] = *(const float2*)(pin + t * D_);
        xs0 = fmaf(wt, xc[t].x, xs0);
        xs1 = fmaf(wt, xc[t].y, xs1);
    }
    float* attnS = (float*)Xw;
    attnS[mg * 128 + d0]     = xs0;
    attnS[mg * 128 + d0 + 1] = xs1;
    float v0 = attnS[mg * 128 + lane];
    float v1 = attnS[mg * 128 + lane + 64];
    float mx = fmaxf(v0, v1);
    #pragma unroll
    for (int o = 32; o > 0; o >>= 1) mx = fmaxf(mx, __shfl_xor(mx, o));
    float e0 = __expf(v0 - mx), e1 = __expf(v1 - mx);
    float ss = e0 + e1;
    #pragma unroll
    for (int o = 32; o > 0; o >>= 1) ss += __shfl_xor(ss, o);
    float inv = 1.0f / ss;
    attnS[mg * 128 + lane]      = e0 * inv;
    attnS[mg * 128 + lane + 64] = e1 * inv;
    const float a0 = attnS[mg * 128 + d0];
    const float a1 = attnS[mg * 128 + d0 + 1];
    BAR_LDS();

    const int wxbyte = (4 * dh) ^ (mg << 4);
    float* outWp = outW + (size_t)(b0 + mg) * (T1_ * D_) + d0;
    unsigned wx30 = 0;
    #pragma unroll
    for (int t = 0; t < T1_; ++t) {
        float w0 = a0 * xc[t].x, w1 = a1 * xc[t].y;
        f32x2 wsv; wsv[0] = w0; wsv[1] = w1;
        __builtin_nontemporal_store(wsv, (f32x2*)(outWp + t * D_));
        unsigned u = cvt_pk_bf16(w0, w1);
        if (t < 30) *(unsigned*)(Xw + t * 2048 + mg * 256 + wxbyte) = u;
        else        wx30 = u;
    }
    ((unsigned*)Hs)[tid]       = 0u;
    ((unsigned*)Hs)[tid + 512] = 0u;
    BAR_LDS();

    const int arow = l15 & 7;
    const int asw  = arow << 4;
    bf16x8 wxfr[4];
    #pragma unroll
    for (int kf = 0; kf < 4; ++kf)
        wxfr[kf] = *(const bf16x8*)(Xw + arow * 256 + ((kf * 64 + lq * 16) ^ asw));

    const int rb = ((lane & 31) >> 4) * 4 + ((lane >> 5) << 1);
    const bool hi32 = (lane >= 32);
    float cs0 = 0.f, cs1 = 0.f;
    float* outE0 = outE + (size_t)(b0 + rb)     * (T1_ * D_) + col;
    float* outE1 = outE + (size_t)(b0 + rb + 1) * (T1_ * D_) + col;

    for (int t = 0; t < T1_; ++t) {
        const char* hp = Hs + (t & 1) * 2048 + arow * 256;
        bf16x8 hfr[4];
        #pragma unroll
        for (int kf = 0; kf < 4; ++kf)
            hfr[kf] = *(const bf16x8*)(hp + ((kf * 64 + lq * 16) ^ asw));
        if (t == 1)
            *(unsigned*)(Xw + mg * 256 + wxbyte) = wx30;
        f32x4 accx[4];
        #pragma unroll
        for (int s = 0; s < 4; ++s) {
            f32x4 a_ = {0.f, 0.f, 0.f, 0.f};
            #pragma unroll
            for (int kf = 0; kf < 4; ++kf)
                a_ = __builtin_amdgcn_mfma_f32_16x16x32_bf16(wxfr[kf], bw[s][kf], a_, 0, 0, 0);
            accx[s] = a_;
        }
        f32x4 acc[4];
        #pragma unroll
        for (int s = 0; s < 4; ++s) {
            f32x4 zA = {0.f, 0.f, 0.f, 0.f};
            f32x4 zB = {0.f, 0.f, 0.f, 0.f};
            zA = __builtin_amdgcn_mfma_f32_16x16x32_bf16(hfr[0], bw[s][4], zA, 0, 0, 0);
            zB = __builtin_amdgcn_mfma_f32_16x16x32_bf16(hfr[2], bw[s][6], zB, 0, 0, 0);
            zA = __builtin_amdgcn_mfma_f32_16x16x32_bf16(hfr[1], bw[s][5], zA, 0, 0, 0);
            zB = __builtin_amdgcn_mfma_f32_16x16x32_bf16(hfr[3], bw[s][7], zB, 0, 0, 0);
            acc[s] = accx[s] + zA + zB;
        }
        if (t < 30) {
            int slot = (t + 1 == 30) ? 0 : (t + 1);
            #pragma unroll
            for (int kf = 0; kf < 4; ++kf)
                wxfr[kf] = *(const bf16x8*)(Xw + slot * 2048 + arow * 256 + ((kf * 64 + lq * 16) ^ asw));
        }
        float gq0[4], gq1[4];
        #pragma unroll
        for (int s = 0; s < 4; ++s) {
            gq0[s] = hi32 ? acc[s][2] : acc[s][0];
            gq1[s] = hi32 ? acc[s][3] : acc[s][1];
        }
        float iv, fv, gv, ov, cn, hh0, hh1;
        iv = gq0[0] + bs0; fv = gq0[1] + bs1; gv = gq0[2] + bs2; ov = gq0[3] + bs3;
        cn = sigf(fv) * cs0 + sigf(iv) * tanhf_(gv); cs0 = cn;
        hh0 = sigf(ov) * tanhf_(cn);
        iv = gq1[0] + bs0; fv = gq1[1] + bs1; gv = gq1[2] + bs2; ov = gq1[3] + bs3;
        cn = sigf(fv) * cs1 + sigf(iv) * tanhf_(gv); cs1 = cn;
        hh1 = sigf(ov) * tanhf_(cn);
        unsigned hu = cvt_pk_bf16(hh0, hh1);
        if (t < 30) {
            char* hw = Hs + ((t + 1) & 1) * 2048;
            *(unsigned short*)(hw + rb * 256       + ((2 * col) ^ (rb << 4)))       = (unsigned short)(hu & 0xffffu);
            *(unsigned short*)(hw + (rb + 1) * 256 + ((2 * col) ^ ((rb + 1) << 4))) = (unsigned short)(hu >> 16);
        }
        __builtin_nontemporal_store(hh0, outE0 + t * D_);
        __builtin_nontemporal_store(hh1, outE1 + t * D_);
        BAR_LDS();
    }
}

extern "C" void kernel_launch(void* const* d_in, const int* in_sizes, int n_in,
                              void* d_out, int out_size, void* d_ws, size_t ws_size,
                              hipStream_t stream) {
    const float* in  = (const float*)d_in[0];
    const float* Wih = (const float*)d_in[1];
    const float* Whh = (const float*)d_in[2];
    const float* bih = (const float*)d_in[3];
    const float* bhh = (const float*)d_in[4];
    const float* aw  = (const float*)d_in[5];

    float* outW = (float*)d_out;
    float* outE = outW + (size_t)B_ * T1_ * D_;

    if (ws_size >= (size_t)(B_ / MB_) * WS_PER_BLK) {
        enc_ws<<<dim3(B_ / MB_), dim3(512), 0, stream>>>(in, Wih, Whh, bih, bhh, aw,
                                                         outW, outE, (char*)d_ws);
    } else {
        enc_fused<<<dim3(B_ / MB_), dim3(512), 0, stream>>>(in, Wih, Whh, bih, bhh, aw,
                                                            outW, outE);
    }
}